// Round 8
// baseline (251.791 us; speedup 1.0000x reference)
//
#include <hip/hip_runtime.h>

#define NN 3000
#define NB 8
#define TP 12
#define DMAX 128
#define F1T 480    // block-1 packed features: h(8*24) + d(8*12) + w(8*24)
#define F2T 768    // block-2 packed features: 3 * 8 * 32
#define Z1T 1536   // z1 packed: 3 * 8 * 64

struct BrW {
    const float *W1[3]; const float *b1[3]; const float *c1w[3]; const float *c1b[3];
    const float *W2[3]; const float *b2[3]; const float *c2w[3]; const float *c2b[3];
    const float *Fb[3];
};

// ---------------- one-pass Laplacian build: degree + ballot-compact ----------------
__global__ void build_kernel(const float* __restrict__ A, int* __restrict__ colp,
                             float* __restrict__ valp, int* __restrict__ cnt,
                             float* __restrict__ dinv) {
    int n = blockIdx.x;
    int lane = threadIdx.x;
    const float* row = A + (size_t)n * NN;
    int base = 0;
    float s = 0.f;
    for (int start = 0; start < NN; start += 64) {
        int m = start + lane;
        float a = 0.f; bool nz = false;
        if (m < NN && m != n) {
            a = row[m];
            nz = (a != 0.f);
        }
        s += a;
        unsigned long long mask = __ballot(nz);
        int off = __popcll(mask & ((1ull << lane) - 1ull));
        if (nz) {
            int idx = base + off;
            if (idx < DMAX) { colp[n * DMAX + idx] = m; valp[n * DMAX + idx] = a; }
        }
        base += __popcll(mask);
    }
    for (int o = 32; o > 0; o >>= 1) s += __shfl_down(s, o);
    if (lane == 0) {
        cnt[n] = (base < DMAX) ? base : DMAX;
        dinv[n] = (s > 0.f) ? 1.0f / sqrtf(s) : 0.f;
    }
}

__global__ void scale_kernel(const int* __restrict__ colp, float* __restrict__ valp,
                             const int* __restrict__ cnt, const float* __restrict__ dinv) {
    int n = blockIdx.x;
    int j = threadIdx.x;
    if (j < cnt[n]) {
        int m = colp[n * DMAX + j];
        valp[n * DMAX + j] *= -dinv[n] * dinv[m];
    }
}

// ---------------- pack Xh|Xd|Xw (B,N,1,T) -> xcat (N, 480) ----------------
__global__ void pack_kernel(const float* __restrict__ Xh, const float* __restrict__ Xd,
                            const float* __restrict__ Xw, float* __restrict__ xcat) {
    int idx = blockIdx.x * blockDim.x + threadIdx.x;
    if (idx >= NN * F1T) return;
    int n = idx / F1T, r = idx % F1T;
    const float* src; int b, t, T;
    if (r < 192)      { src = Xh; T = 24; int rr = r;       b = rr / 24; t = rr % 24; }
    else if (r < 288) { src = Xd; T = 12; int rr = r - 192; b = rr / 12; t = rr % 12; }
    else              { src = Xw; T = 24; int rr = r - 288; b = rr / 24; t = rr % 24; }
    xcat[idx] = src[((size_t)b * NN + n) * T + t];
}

// ---------------- SpMM, float2-per-thread gathers + 8-deep ILP ----------------
// EPI 0: y = Lx ; EPI 1: y = 2*Lx - aux ; EPI 2: y = aux + 2*Lx
template <int F, int EPI>
__global__ void spmm_kernel(const int* __restrict__ colp, const float* __restrict__ valp,
                            const int* __restrict__ cnt, const float* __restrict__ x,
                            const float* __restrict__ aux, float* __restrict__ y) {
    constexpr int FH = F / 2;               // float2 units per row
    int n = blockIdx.x;
    int fp = blockIdx.y * 256 + threadIdx.x;  // pair index
    __shared__ int   scol[DMAX];
    __shared__ float sval[DMAX];
    int c = cnt[n];
    if (threadIdx.x < DMAX) {
        int j = threadIdx.x;
        bool ok = j < c;
        scol[j] = ok ? colp[n * DMAX + j] * FH : 0;
        sval[j] = ok ? valp[n * DMAX + j] : 0.f;
    }
    __syncthreads();
    int c8 = (c + 7) & ~7;
    const float2* x2 = reinterpret_cast<const float2*>(x);
    float2 a0 = {0.f, 0.f}, a1 = {0.f, 0.f}, a2 = {0.f, 0.f}, a3 = {0.f, 0.f};
    if (fp < FH) {
        for (int i = 0; i < c8; i += 8) {
            int   c0 = scol[i + 0], c1 = scol[i + 1], c2 = scol[i + 2], c3 = scol[i + 3];
            int   c4 = scol[i + 4], c5 = scol[i + 5], c6 = scol[i + 6], c7 = scol[i + 7];
            float w0 = sval[i + 0], w1 = sval[i + 1], w2 = sval[i + 2], w3 = sval[i + 3];
            float w4 = sval[i + 4], w5 = sval[i + 5], w6 = sval[i + 6], w7 = sval[i + 7];
            float2 g0 = x2[c0 + fp], g1 = x2[c1 + fp], g2 = x2[c2 + fp], g3 = x2[c3 + fp];
            float2 g4 = x2[c4 + fp], g5 = x2[c5 + fp], g6 = x2[c6 + fp], g7 = x2[c7 + fp];
            a0.x += w0 * g0.x; a0.y += w0 * g0.y;  a1.x += w1 * g1.x; a1.y += w1 * g1.y;
            a2.x += w2 * g2.x; a2.y += w2 * g2.y;  a3.x += w3 * g3.x; a3.y += w3 * g3.y;
            a0.x += w4 * g4.x; a0.y += w4 * g4.y;  a1.x += w5 * g5.x; a1.y += w5 * g5.y;
            a2.x += w6 * g6.x; a2.y += w6 * g6.y;  a3.x += w7 * g7.x; a3.y += w7 * g7.y;
        }
    }
    if (fp >= FH) return;
    float2 acc;
    acc.x = (a0.x + a1.x) + (a2.x + a3.x);
    acc.y = (a0.y + a1.y) + (a2.y + a3.y);
    size_t o = (size_t)n * FH + fp;
    if (EPI == 1) {
        float2 ax = reinterpret_cast<const float2*>(aux)[o];
        acc.x = 2.f * acc.x - ax.x; acc.y = 2.f * acc.y - ax.y;
    } else if (EPI == 2) {
        float2 ax = reinterpret_cast<const float2*>(aux)[o];
        acc.x = ax.x + 2.f * acc.x; acc.y = ax.y + 2.f * acc.y;
    }
    reinterpret_cast<float2*>(y)[o] = acc;
}

// ---------------- block-1 combine: cheb + bias + relu + tconv + relu ----------------
template <int T, int OFF, int BROFF>
__global__ void combine1_kernel(const float* __restrict__ xcat, const float* __restrict__ t1cat,
                                const float* __restrict__ t2cat, float* __restrict__ z1cat,
                                const float* __restrict__ W, const float* __restrict__ bg,
                                const float* __restrict__ cw, const float* __restrict__ cb) {
    int wid = threadIdx.x >> 6;
    int co = threadIdx.x & 63;
    int unit = blockIdx.x * 4 + wid;  // 0 .. 23999
    int n = unit / NB, b = unit % NB;
    size_t rowbase = (size_t)n * F1T + OFF + b * T;
    float xv0 = 0.f, xv1 = 0.f, xv2 = 0.f;
    if (co < T) {
        xv0 = xcat[rowbase + co];
        xv1 = t1cat[rowbase + co];
        xv2 = t2cat[rowbase + co];
    }
    float acc = bg[co];
    #pragma unroll
    for (int i = 0; i < T; ++i)
        acc += __shfl(xv0, i) * W[i * 64 + co];
    #pragma unroll
    for (int i = 0; i < T; ++i)
        acc += __shfl(xv1, i) * W[(T + i) * 64 + co];
    #pragma unroll
    for (int i = 0; i < T; ++i)
        acc += __shfl(xv2, i) * W[(2 * T + i) * 64 + co];
    float z = fmaxf(acc, 0.f);
    float left  = __shfl_up(z, 1);
    float right = __shfl_down(z, 1);
    if (co == 0) left = 0.f;
    if (co == 63) right = 0.f;
    float w0 = cw[0], w1 = cw[1], w2 = cw[2], bb = cb[0];
    float o = fmaxf(w0 * left + w1 * z + w2 * right + bb, 0.f);
    z1cat[(size_t)n * Z1T + BROFF + b * 64 + co] = o;
}

// ---------------- tiled y-GEMM: 96 rows x 96 cols per block, K=64 ----------------
// Each thread: 3 rows x 12 cols (36 acc). sW interleaved c = j*3 + m.
#define GR 96
__global__ void __launch_bounds__(256, 2)
gemmy_kernel(const float* __restrict__ z1cat, float* __restrict__ y1cat,
             float* __restrict__ y2cat, float* __restrict__ c0cat, BrW P) {
    int tile = blockIdx.x;   // 0..249
    int br = blockIdx.y;
    __shared__ float sW[64 * 96];        // 24 KB; sW[k*96 + j*3 + m] = W[m][k][j]
    __shared__ float sZ[GR][65];         // 24.4 KB, padded
    const float* W = P.W2[br];           // (3, 64, 32)
    for (int i = threadIdx.x; i < 6144; i += 256) {
        int k = i / 96, c = i % 96;
        int j = c / 3, m = c % 3;
        sW[i] = W[m * 2048 + k * 32 + j];
    }
    int row0 = tile * GR;
    for (int i = threadIdx.x; i < GR * 64; i += 256) {
        int r = i >> 6, k = i & 63;
        int rg = row0 + r;
        int n = rg >> 3, b = rg & 7;
        sZ[r][k] = z1cat[(size_t)n * Z1T + br * 512 + b * 64 + k];
    }
    __syncthreads();

    int rq = threadIdx.x >> 3;       // 0..31 -> rows rq*3 .. rq*3+2
    int g = threadIdx.x & 7;         // cols g*12 .. g*12+11
    float acc[3][12];
    #pragma unroll
    for (int rr = 0; rr < 3; ++rr)
        #pragma unroll
        for (int j = 0; j < 12; ++j) acc[rr][j] = 0.f;

    #pragma unroll 4
    for (int k = 0; k < 64; ++k) {
        const float4* wr = reinterpret_cast<const float4*>(sW + k * 96 + g * 12);
        float4 wa = wr[0], wb = wr[1], wc = wr[2];
        #pragma unroll
        for (int rr = 0; rr < 3; ++rr) {
            float zv = sZ[rq * 3 + rr][k];
            acc[rr][0] += zv * wa.x; acc[rr][1] += zv * wa.y;
            acc[rr][2] += zv * wa.z; acc[rr][3] += zv * wa.w;
            acc[rr][4] += zv * wb.x; acc[rr][5] += zv * wb.y;
            acc[rr][6] += zv * wb.z; acc[rr][7] += zv * wb.w;
            acc[rr][8] += zv * wc.x; acc[rr][9] += zv * wc.y;
            acc[rr][10] += zv * wc.z; acc[rr][11] += zv * wc.w;
        }
    }

    const float* b2 = P.b2[br];
    float bj0 = b2[g * 4 + 0], bj1 = b2[g * 4 + 1], bj2 = b2[g * 4 + 2], bj3 = b2[g * 4 + 3];
    #pragma unroll
    for (int rr = 0; rr < 3; ++rr) {
        int rg = row0 + rq * 3 + rr;
        int n = rg >> 3, b = rg & 7;
        size_t obase = (size_t)n * F2T + br * 256 + b * 32;
        float bj[4] = {bj0, bj1, bj2, bj3};
        #pragma unroll
        for (int jj = 0; jj < 4; ++jj) {
            int j = g * 4 + jj;
            float a0 = acc[rr][jj * 3 + 0], a1 = acc[rr][jj * 3 + 1], a2 = acc[rr][jj * 3 + 2];
            y1cat[obase + j] = a1;
            y2cat[obase + j] = a2;
            c0cat[obase + j] = a0 - a2 + bj[jj];
        }
    }
}

// ---------------- block-2 combine + final linear + fusion, per node ----------------
__global__ void combine2_final_kernel(const float* __restrict__ c0cat,
                                      const float* __restrict__ vcat,
                                      const float* __restrict__ WD, const float* __restrict__ bD,
                                      float* __restrict__ out, BrW P) {
    int n = blockIdx.x;
    __shared__ float z2[3][NB][32];
    int unit = threadIdx.x >> 5;      // 0..23
    int co = threadIdx.x & 31;
    int br = unit >> 3, b = unit & 7;
    size_t o = (size_t)n * F2T + br * 256 + b * 32 + co;
    float a = fmaxf(c0cat[o] + vcat[o], 0.f);
    float left  = __shfl_up(a, 1);
    float right = __shfl_down(a, 1);
    if (co == 0) left = 0.f;
    if (co == 31) right = 0.f;
    float w0 = P.c2w[br][0], w1 = P.c2w[br][1], w2 = P.c2w[br][2], bb = P.c2b[br][0];
    z2[br][b][co] = fmaxf(w0 * left + w1 * a + w2 * right + bb, 0.f);
    __syncthreads();
    if (threadIdx.x < NB * TP) {
        int b2 = threadIdx.x / TP, tp = threadIdx.x % TP;
        float y = 0.f;
        for (int brr = 0; brr < 3; ++brr) {
            float s = bD[tp];
            const float* zz = z2[brr][b2];
            for (int c = 0; c < 32; ++c) s += zz[c] * WD[c * TP + tp];
            y += fmaxf(s, 0.f) * P.Fb[brr][tp];
        }
        out[((size_t)b2 * NN + n) * TP + tp] = y;
    }
}

// ---------------- launcher ----------------

static inline size_t align256(size_t x) { return (x + 255) & ~(size_t)255; }

extern "C" void kernel_launch(void* const* d_in, const int* in_sizes, int n_in,
                              void* d_out, int out_size, void* d_ws, size_t ws_size,
                              hipStream_t stream) {
    const float* Xh = (const float*)d_in[0];
    const float* Xd = (const float*)d_in[1];
    const float* Xw = (const float*)d_in[2];
    const float* A  = (const float*)d_in[3];
    const float* WD = (const float*)d_in[28];
    const float* bD = (const float*)d_in[29];

    BrW P;
    for (int br = 0; br < 3; ++br) {
        int base = 4 + br * 8;
        P.W1[br]  = (const float*)d_in[base + 0];
        P.b1[br]  = (const float*)d_in[base + 1];
        P.c1w[br] = (const float*)d_in[base + 2];
        P.c1b[br] = (const float*)d_in[base + 3];
        P.W2[br]  = (const float*)d_in[base + 4];
        P.b2[br]  = (const float*)d_in[base + 5];
        P.c2w[br] = (const float*)d_in[base + 6];
        P.c2b[br] = (const float*)d_in[base + 7];
        P.Fb[br]  = (const float*)d_in[30 + br];
    }

    char* p = (char*)d_ws;
    int*   colp  = (int*)p;   p += align256((size_t)NN * DMAX * 4);
    float* valp  = (float*)p; p += align256((size_t)NN * DMAX * 4);
    int*   cnt   = (int*)p;   p += align256(NN * 4);
    float* dinv  = (float*)p; p += align256(NN * 4);
    float* xcat  = (float*)p; p += align256((size_t)NN * F1T * 4);
    float* t1cat = (float*)p; p += align256((size_t)NN * F1T * 4);
    float* t2cat = (float*)p; p += align256((size_t)NN * F1T * 4);
    float* z1cat = (float*)p; p += align256((size_t)NN * Z1T * 4);
    float* y1cat = (float*)p; p += align256((size_t)NN * F2T * 4);
    float* y2cat = (float*)p; p += align256((size_t)NN * F2T * 4);
    float* c0cat = (float*)p; p += align256((size_t)NN * F2T * 4);
    float* scat  = (float*)p; p += align256((size_t)NN * F2T * 4);
    float* vcat  = (float*)p; p += align256((size_t)NN * F2T * 4);

    build_kernel<<<NN, 64, 0, stream>>>(A, colp, valp, cnt, dinv);
    scale_kernel<<<NN, DMAX, 0, stream>>>(colp, valp, cnt, dinv);
    pack_kernel<<<(NN * F1T + 255) / 256, 256, 0, stream>>>(Xh, Xd, Xw, xcat);

    // Block 1 (all branches packed, F=480 -> 240 float2): t1 = L x ; t2 = 2 L t1 - x
    spmm_kernel<F1T, 0><<<dim3(NN, 1), 256, 0, stream>>>(colp, valp, cnt, xcat, nullptr, t1cat);
    spmm_kernel<F1T, 1><<<dim3(NN, 1), 256, 0, stream>>>(colp, valp, cnt, t1cat, xcat, t2cat);
    combine1_kernel<24, 0, 0><<<6000, 256, 0, stream>>>(
        xcat, t1cat, t2cat, z1cat, P.W1[0], P.b1[0], P.c1w[0], P.c1b[0]);
    combine1_kernel<12, 192, 512><<<6000, 256, 0, stream>>>(
        xcat, t1cat, t2cat, z1cat, P.W1[1], P.b1[1], P.c1w[1], P.c1b[1]);
    combine1_kernel<24, 288, 1024><<<6000, 256, 0, stream>>>(
        xcat, t1cat, t2cat, z1cat, P.W1[2], P.b1[2], P.c1w[2], P.c1b[2]);

    // Block 2 W-first: y1,y2,c0 ; s = y1 + 2 L y2 ; v = L s ; out2 = relu(c0 + v)...
    gemmy_kernel<<<dim3(250, 3), 256, 0, stream>>>(z1cat, y1cat, y2cat, c0cat, P);
    spmm_kernel<F2T, 2><<<dim3(NN, 2), 256, 0, stream>>>(colp, valp, cnt, y2cat, y1cat, scat);
    spmm_kernel<F2T, 0><<<dim3(NN, 2), 256, 0, stream>>>(colp, valp, cnt, scat, nullptr, vcat);

    combine2_final_kernel<<<NN, 768, 0, stream>>>(c0cat, vcat, WD, bD, (float*)d_out, P);
}

// Round 9
// 213.283 us; speedup vs baseline: 1.1806x; 1.1806x over previous
//
#include <hip/hip_runtime.h>

#define NN 3000
#define NB 8
#define TP 12
#define DMAX 128
#define F1T 480    // block-1 packed features: h(8*24) + d(8*12) + w(8*24)
#define F2T 768    // block-2 packed features: 3 * 8 * 32
#define Z1T 1536   // z1 packed: 3 * 8 * 64

struct BrW {
    const float *W1[3]; const float *b1[3]; const float *c1w[3]; const float *c1b[3];
    const float *W2[3]; const float *b2[3]; const float *c2w[3]; const float *c2b[3];
    const float *Fb[3];
};

// ---------------- one-pass Laplacian build: degree + ballot-compact ----------------
__global__ void build_kernel(const float* __restrict__ A, int* __restrict__ colp,
                             float* __restrict__ valp, int* __restrict__ cnt,
                             float* __restrict__ dinv) {
    int n = blockIdx.x;
    int lane = threadIdx.x;
    const float* row = A + (size_t)n * NN;
    int base = 0;
    float s = 0.f;
    for (int start = 0; start < NN; start += 64) {
        int m = start + lane;
        float a = 0.f; bool nz = false;
        if (m < NN && m != n) {
            a = row[m];
            nz = (a != 0.f);
        }
        s += a;
        unsigned long long mask = __ballot(nz);
        int off = __popcll(mask & ((1ull << lane) - 1ull));
        if (nz) {
            int idx = base + off;
            if (idx < DMAX) { colp[n * DMAX + idx] = m; valp[n * DMAX + idx] = a; }
        }
        base += __popcll(mask);
    }
    for (int o = 32; o > 0; o >>= 1) s += __shfl_down(s, o);
    if (lane == 0) {
        cnt[n] = (base < DMAX) ? base : DMAX;
        dinv[n] = (s > 0.f) ? 1.0f / sqrtf(s) : 0.f;
    }
}

__global__ void scale_kernel(const int* __restrict__ colp, float* __restrict__ valp,
                             const int* __restrict__ cnt, const float* __restrict__ dinv) {
    int n = blockIdx.x;
    int j = threadIdx.x;
    if (j < cnt[n]) {
        int m = colp[n * DMAX + j];
        valp[n * DMAX + j] *= -dinv[n] * dinv[m];
    }
}

// ---------------- pack Xh|Xd|Xw (B,N,1,T) -> xcat (N, 480) ----------------
__global__ void pack_kernel(const float* __restrict__ Xh, const float* __restrict__ Xd,
                            const float* __restrict__ Xw, float* __restrict__ xcat) {
    int idx = blockIdx.x * blockDim.x + threadIdx.x;
    if (idx >= NN * F1T) return;
    int n = idx / F1T, r = idx % F1T;
    const float* src; int b, t, T;
    if (r < 192)      { src = Xh; T = 24; int rr = r;       b = rr / 24; t = rr % 24; }
    else if (r < 288) { src = Xd; T = 12; int rr = r - 192; b = rr / 12; t = rr % 12; }
    else              { src = Xw; T = 24; int rr = r - 288; b = rr / 24; t = rr % 24; }
    xcat[idx] = src[((size_t)b * NN + n) * T + t];
}

// ---------------- SpMM, scalar gathers, 16-deep ILP ----------------
// EPI 0: y = Lx ; EPI 1: y = 2*Lx - aux ; EPI 2: y = aux + 2*Lx
template <int F, int EPI>
__global__ void spmm_kernel(const int* __restrict__ colp, const float* __restrict__ valp,
                            const int* __restrict__ cnt, const float* __restrict__ x,
                            const float* __restrict__ aux, float* __restrict__ y) {
    int n = blockIdx.x;
    int f = blockIdx.y * 256 + threadIdx.x;
    __shared__ int   scol[DMAX];
    __shared__ float sval[DMAX];
    int c = cnt[n];
    if (threadIdx.x < DMAX) {
        int j = threadIdx.x;
        bool ok = j < c;
        scol[j] = ok ? colp[n * DMAX + j] * F : 0;
        sval[j] = ok ? valp[n * DMAX + j] : 0.f;
    }
    __syncthreads();
    int c16 = (c + 15) & ~15;
    float a0 = 0.f, a1 = 0.f, a2 = 0.f, a3 = 0.f;
    float a4 = 0.f, a5 = 0.f, a6 = 0.f, a7 = 0.f;
    if (f < F) {
        for (int i = 0; i < c16; i += 16) {
            float g[16], w[16];
            #pragma unroll
            for (int u = 0; u < 16; ++u) {
                int cc = scol[i + u];
                w[u] = sval[i + u];
                g[u] = x[cc + f];
            }
            a0 += w[0] * g[0];   a1 += w[1] * g[1];
            a2 += w[2] * g[2];   a3 += w[3] * g[3];
            a4 += w[4] * g[4];   a5 += w[5] * g[5];
            a6 += w[6] * g[6];   a7 += w[7] * g[7];
            a0 += w[8] * g[8];   a1 += w[9] * g[9];
            a2 += w[10] * g[10]; a3 += w[11] * g[11];
            a4 += w[12] * g[12]; a5 += w[13] * g[13];
            a6 += w[14] * g[14]; a7 += w[15] * g[15];
        }
    }
    if (f >= F) return;
    float acc = ((a0 + a1) + (a2 + a3)) + ((a4 + a5) + (a6 + a7));
    size_t o = (size_t)n * F + f;
    if (EPI == 1) acc = 2.f * acc - aux[o];
    else if (EPI == 2) acc = aux[o] + 2.f * acc;
    y[o] = acc;
}

// ---------------- block-1 combine: cheb + bias + relu + tconv + relu ----------------
template <int T, int OFF, int BROFF>
__global__ void combine1_kernel(const float* __restrict__ xcat, const float* __restrict__ t1cat,
                                const float* __restrict__ t2cat, float* __restrict__ z1cat,
                                const float* __restrict__ W, const float* __restrict__ bg,
                                const float* __restrict__ cw, const float* __restrict__ cb) {
    int wid = threadIdx.x >> 6;
    int co = threadIdx.x & 63;
    int unit = blockIdx.x * 4 + wid;  // 0 .. 23999
    int n = unit / NB, b = unit % NB;
    size_t rowbase = (size_t)n * F1T + OFF + b * T;
    float xv0 = 0.f, xv1 = 0.f, xv2 = 0.f;
    if (co < T) {
        xv0 = xcat[rowbase + co];
        xv1 = t1cat[rowbase + co];
        xv2 = t2cat[rowbase + co];
    }
    float acc = bg[co];
    #pragma unroll
    for (int i = 0; i < T; ++i)
        acc += __shfl(xv0, i) * W[i * 64 + co];
    #pragma unroll
    for (int i = 0; i < T; ++i)
        acc += __shfl(xv1, i) * W[(T + i) * 64 + co];
    #pragma unroll
    for (int i = 0; i < T; ++i)
        acc += __shfl(xv2, i) * W[(2 * T + i) * 64 + co];
    float z = fmaxf(acc, 0.f);
    float left  = __shfl_up(z, 1);
    float right = __shfl_down(z, 1);
    if (co == 0) left = 0.f;
    if (co == 63) right = 0.f;
    float w0 = cw[0], w1 = cw[1], w2 = cw[2], bb = cb[0];
    float o = fmaxf(w0 * left + w1 * z + w2 * right + bb, 0.f);
    z1cat[(size_t)n * Z1T + BROFF + b * 64 + co] = o;
}

// ---------------- tiled y-GEMM: 96 rows x 96 cols per block, K=64 ----------------
// Each thread: 3 rows x 12 cols (36 acc). sW interleaved c = j*3 + m.
#define GR 96
__global__ void __launch_bounds__(256, 2)
gemmy_kernel(const float* __restrict__ z1cat, float* __restrict__ y1cat,
             float* __restrict__ y2cat, float* __restrict__ c0cat, BrW P) {
    int tile = blockIdx.x;   // 0..249
    int br = blockIdx.y;
    __shared__ float sW[64 * 96];        // 24 KB; sW[k*96 + j*3 + m] = W[m][k][j]
    __shared__ float sZ[GR][65];         // 24.4 KB, padded
    const float* W = P.W2[br];           // (3, 64, 32)
    for (int i = threadIdx.x; i < 6144; i += 256) {
        int k = i / 96, c = i % 96;
        int j = c / 3, m = c % 3;
        sW[i] = W[m * 2048 + k * 32 + j];
    }
    int row0 = tile * GR;
    for (int i = threadIdx.x; i < GR * 64; i += 256) {
        int r = i >> 6, k = i & 63;
        int rg = row0 + r;
        int n = rg >> 3, b = rg & 7;
        sZ[r][k] = z1cat[(size_t)n * Z1T + br * 512 + b * 64 + k];
    }
    __syncthreads();

    int rq = threadIdx.x >> 3;       // 0..31 -> rows rq*3 .. rq*3+2
    int g = threadIdx.x & 7;         // cols g*12 .. g*12+11
    float acc[3][12];
    #pragma unroll
    for (int rr = 0; rr < 3; ++rr)
        #pragma unroll
        for (int j = 0; j < 12; ++j) acc[rr][j] = 0.f;

    #pragma unroll 4
    for (int k = 0; k < 64; ++k) {
        const float4* wr = reinterpret_cast<const float4*>(sW + k * 96 + g * 12);
        float4 wa = wr[0], wb = wr[1], wc = wr[2];
        #pragma unroll
        for (int rr = 0; rr < 3; ++rr) {
            float zv = sZ[rq * 3 + rr][k];
            acc[rr][0] += zv * wa.x; acc[rr][1] += zv * wa.y;
            acc[rr][2] += zv * wa.z; acc[rr][3] += zv * wa.w;
            acc[rr][4] += zv * wb.x; acc[rr][5] += zv * wb.y;
            acc[rr][6] += zv * wb.z; acc[rr][7] += zv * wb.w;
            acc[rr][8] += zv * wc.x; acc[rr][9] += zv * wc.y;
            acc[rr][10] += zv * wc.z; acc[rr][11] += zv * wc.w;
        }
    }

    const float* b2 = P.b2[br];
    float bj0 = b2[g * 4 + 0], bj1 = b2[g * 4 + 1], bj2 = b2[g * 4 + 2], bj3 = b2[g * 4 + 3];
    #pragma unroll
    for (int rr = 0; rr < 3; ++rr) {
        int rg = row0 + rq * 3 + rr;
        int n = rg >> 3, b = rg & 7;
        size_t obase = (size_t)n * F2T + br * 256 + b * 32;
        float bj[4] = {bj0, bj1, bj2, bj3};
        #pragma unroll
        for (int jj = 0; jj < 4; ++jj) {
            int j = g * 4 + jj;
            float a0 = acc[rr][jj * 3 + 0], a1 = acc[rr][jj * 3 + 1], a2 = acc[rr][jj * 3 + 2];
            y1cat[obase + j] = a1;
            y2cat[obase + j] = a2;
            c0cat[obase + j] = a0 - a2 + bj[jj];
        }
    }
}

// ---------------- block-2 combine + final linear + fusion, per node ----------------
__global__ void combine2_final_kernel(const float* __restrict__ c0cat,
                                      const float* __restrict__ vcat,
                                      const float* __restrict__ WD, const float* __restrict__ bD,
                                      float* __restrict__ out, BrW P) {
    int n = blockIdx.x;
    __shared__ float z2[3][NB][32];
    int unit = threadIdx.x >> 5;      // 0..23
    int co = threadIdx.x & 31;
    int br = unit >> 3, b = unit & 7;
    size_t o = (size_t)n * F2T + br * 256 + b * 32 + co;
    float a = fmaxf(c0cat[o] + vcat[o], 0.f);
    float left  = __shfl_up(a, 1);
    float right = __shfl_down(a, 1);
    if (co == 0) left = 0.f;
    if (co == 31) right = 0.f;
    float w0 = P.c2w[br][0], w1 = P.c2w[br][1], w2 = P.c2w[br][2], bb = P.c2b[br][0];
    z2[br][b][co] = fmaxf(w0 * left + w1 * a + w2 * right + bb, 0.f);
    __syncthreads();
    if (threadIdx.x < NB * TP) {
        int b2 = threadIdx.x / TP, tp = threadIdx.x % TP;
        float y = 0.f;
        for (int brr = 0; brr < 3; ++brr) {
            float s = bD[tp];
            const float* zz = z2[brr][b2];
            for (int c = 0; c < 32; ++c) s += zz[c] * WD[c * TP + tp];
            y += fmaxf(s, 0.f) * P.Fb[brr][tp];
        }
        out[((size_t)b2 * NN + n) * TP + tp] = y;
    }
}

// ---------------- launcher ----------------

static inline size_t align256(size_t x) { return (x + 255) & ~(size_t)255; }

extern "C" void kernel_launch(void* const* d_in, const int* in_sizes, int n_in,
                              void* d_out, int out_size, void* d_ws, size_t ws_size,
                              hipStream_t stream) {
    const float* Xh = (const float*)d_in[0];
    const float* Xd = (const float*)d_in[1];
    const float* Xw = (const float*)d_in[2];
    const float* A  = (const float*)d_in[3];
    const float* WD = (const float*)d_in[28];
    const float* bD = (const float*)d_in[29];

    BrW P;
    for (int br = 0; br < 3; ++br) {
        int base = 4 + br * 8;
        P.W1[br]  = (const float*)d_in[base + 0];
        P.b1[br]  = (const float*)d_in[base + 1];
        P.c1w[br] = (const float*)d_in[base + 2];
        P.c1b[br] = (const float*)d_in[base + 3];
        P.W2[br]  = (const float*)d_in[base + 4];
        P.b2[br]  = (const float*)d_in[base + 5];
        P.c2w[br] = (const float*)d_in[base + 6];
        P.c2b[br] = (const float*)d_in[base + 7];
        P.Fb[br]  = (const float*)d_in[30 + br];
    }

    char* p = (char*)d_ws;
    int*   colp  = (int*)p;   p += align256((size_t)NN * DMAX * 4);
    float* valp  = (float*)p; p += align256((size_t)NN * DMAX * 4);
    int*   cnt   = (int*)p;   p += align256(NN * 4);
    float* dinv  = (float*)p; p += align256(NN * 4);
    float* xcat  = (float*)p; p += align256((size_t)NN * F1T * 4);
    float* t1cat = (float*)p; p += align256((size_t)NN * F1T * 4);
    float* t2cat = (float*)p; p += align256((size_t)NN * F1T * 4);
    float* z1cat = (float*)p; p += align256((size_t)NN * Z1T * 4);
    float* y1cat = (float*)p; p += align256((size_t)NN * F2T * 4);
    float* y2cat = (float*)p; p += align256((size_t)NN * F2T * 4);
    float* c0cat = (float*)p; p += align256((size_t)NN * F2T * 4);
    float* scat  = (float*)p; p += align256((size_t)NN * F2T * 4);
    float* vcat  = (float*)p; p += align256((size_t)NN * F2T * 4);

    build_kernel<<<NN, 64, 0, stream>>>(A, colp, valp, cnt, dinv);
    scale_kernel<<<NN, DMAX, 0, stream>>>(colp, valp, cnt, dinv);
    pack_kernel<<<(NN * F1T + 255) / 256, 256, 0, stream>>>(Xh, Xd, Xw, xcat);

    // Block 1 (all branches packed, F=480): t1 = L x ; t2 = 2 L t1 - x
    spmm_kernel<F1T, 0><<<dim3(NN, 2), 256, 0, stream>>>(colp, valp, cnt, xcat, nullptr, t1cat);
    spmm_kernel<F1T, 1><<<dim3(NN, 2), 256, 0, stream>>>(colp, valp, cnt, t1cat, xcat, t2cat);
    combine1_kernel<24, 0, 0><<<6000, 256, 0, stream>>>(
        xcat, t1cat, t2cat, z1cat, P.W1[0], P.b1[0], P.c1w[0], P.c1b[0]);
    combine1_kernel<12, 192, 512><<<6000, 256, 0, stream>>>(
        xcat, t1cat, t2cat, z1cat, P.W1[1], P.b1[1], P.c1w[1], P.c1b[1]);
    combine1_kernel<24, 288, 1024><<<6000, 256, 0, stream>>>(
        xcat, t1cat, t2cat, z1cat, P.W1[2], P.b1[2], P.c1w[2], P.c1b[2]);

    // Block 2 W-first: y1,y2,c0 ; s = y1 + 2 L y2 ; v = L s ; out2 = relu(c0 + v)...
    gemmy_kernel<<<dim3(250, 3), 256, 0, stream>>>(z1cat, y1cat, y2cat, c0cat, P);
    spmm_kernel<F2T, 2><<<dim3(NN, 3), 256, 0, stream>>>(colp, valp, cnt, y2cat, y1cat, scat);
    spmm_kernel<F2T, 0><<<dim3(NN, 3), 256, 0, stream>>>(colp, valp, cnt, scat, nullptr, vcat);

    combine2_final_kernel<<<NN, 768, 0, stream>>>(c0cat, vcat, WD, bD, (float*)d_out, P);
}

// Round 10
// 201.621 us; speedup vs baseline: 1.2488x; 1.0578x over previous
//
#include <hip/hip_runtime.h>

#define NN 3000
#define NB 8
#define TP 12
#define DMAX 128
#define F1T 480    // block-1 packed features: h(8*24) + d(8*12) + w(8*24)
#define F2T 768    // block-2 packed features: 3 * 8 * 32
#define Z1T 1536   // z1 packed: 3 * 8 * 64

struct BrW {
    const float *W1[3]; const float *b1[3]; const float *c1w[3]; const float *c1b[3];
    const float *W2[3]; const float *b2[3]; const float *c2w[3]; const float *c2b[3];
    const float *Fb[3];
};

// ---------------- one-pass Laplacian build: degree + ballot-compact ----------------
__global__ void build_kernel(const float* __restrict__ A, int* __restrict__ colp,
                             float* __restrict__ valp, int* __restrict__ cnt,
                             float* __restrict__ dinv) {
    int n = blockIdx.x;
    int lane = threadIdx.x;
    const float* row = A + (size_t)n * NN;
    int base = 0;
    float s = 0.f;
    for (int start = 0; start < NN; start += 64) {
        int m = start + lane;
        float a = 0.f; bool nz = false;
        if (m < NN && m != n) {
            a = row[m];
            nz = (a != 0.f);
        }
        s += a;
        unsigned long long mask = __ballot(nz);
        int off = __popcll(mask & ((1ull << lane) - 1ull));
        if (nz) {
            int idx = base + off;
            if (idx < DMAX) { colp[n * DMAX + idx] = m; valp[n * DMAX + idx] = a; }
        }
        base += __popcll(mask);
    }
    for (int o = 32; o > 0; o >>= 1) s += __shfl_down(s, o);
    if (lane == 0) {
        cnt[n] = (base < DMAX) ? base : DMAX;
        dinv[n] = (s > 0.f) ? 1.0f / sqrtf(s) : 0.f;
    }
}

__global__ void scale_kernel(const int* __restrict__ colp, float* __restrict__ valp,
                             const int* __restrict__ cnt, const float* __restrict__ dinv) {
    int n = blockIdx.x;
    int j = threadIdx.x;
    if (j < cnt[n]) {
        int m = colp[n * DMAX + j];
        valp[n * DMAX + j] *= -dinv[n] * dinv[m];
    }
}

// ---------------- pack Xh|Xd|Xw (B,N,1,T) -> xcat (N, 480) ----------------
__global__ void pack_kernel(const float* __restrict__ Xh, const float* __restrict__ Xd,
                            const float* __restrict__ Xw, float* __restrict__ xcat) {
    int idx = blockIdx.x * blockDim.x + threadIdx.x;
    if (idx >= NN * F1T) return;
    int n = idx / F1T, r = idx % F1T;
    const float* src; int b, t, T;
    if (r < 192)      { src = Xh; T = 24; int rr = r;       b = rr / 24; t = rr % 24; }
    else if (r < 288) { src = Xd; T = 12; int rr = r - 192; b = rr / 12; t = rr % 12; }
    else              { src = Xw; T = 24; int rr = r - 288; b = rr / 24; t = rr % 24; }
    xcat[idx] = src[((size_t)b * NN + n) * T + t];
}

// ---------------- SpMM, scalar gathers, 16-deep ILP, XCD-swizzled slices ----------------
// 1-D grid = NN * ceil(F/SLICE), slice-major work order + bijective XCD swizzle so each
// XCD's gathers stay within <= 2 column-slices (fits 4 MB per-XCD L2).
// EPI 0: y = Lx ; EPI 1: y = 2*Lx - aux ; EPI 2: y = aux + 2*Lx
template <int F, int SLICE, int EPI>
__global__ void spmm_kernel(const int* __restrict__ colp, const float* __restrict__ valp,
                            const int* __restrict__ cnt, const float* __restrict__ x,
                            const float* __restrict__ aux, float* __restrict__ y) {
    int nwg = gridDim.x;
    int q = nwg >> 3;
    int bid = blockIdx.x;
    int w = (bid & 7) * q + (bid >> 3);   // XCD-contiguous chunks (nwg % 8 == 0)
    int slice = w / NN;
    int n = w - slice * NN;
    int f = slice * SLICE + threadIdx.x;

    __shared__ int   scol[DMAX];
    __shared__ float sval[DMAX];
    int c = cnt[n];
    if (threadIdx.x < DMAX) {
        int j = threadIdx.x;
        bool ok = j < c;
        scol[j] = ok ? colp[n * DMAX + j] * F : 0;
        sval[j] = ok ? valp[n * DMAX + j] : 0.f;
    }
    __syncthreads();
    int c16 = (c + 15) & ~15;
    float a0 = 0.f, a1 = 0.f, a2 = 0.f, a3 = 0.f;
    float a4 = 0.f, a5 = 0.f, a6 = 0.f, a7 = 0.f;
    if (f < F) {
        for (int i = 0; i < c16; i += 16) {
            float g[16], w16[16];
            #pragma unroll
            for (int u = 0; u < 16; ++u) {
                int cc = scol[i + u];
                w16[u] = sval[i + u];
                g[u] = x[cc + f];
            }
            a0 += w16[0] * g[0];   a1 += w16[1] * g[1];
            a2 += w16[2] * g[2];   a3 += w16[3] * g[3];
            a4 += w16[4] * g[4];   a5 += w16[5] * g[5];
            a6 += w16[6] * g[6];   a7 += w16[7] * g[7];
            a0 += w16[8] * g[8];   a1 += w16[9] * g[9];
            a2 += w16[10] * g[10]; a3 += w16[11] * g[11];
            a4 += w16[12] * g[12]; a5 += w16[13] * g[13];
            a6 += w16[14] * g[14]; a7 += w16[15] * g[15];
        }
    }
    if (f >= F) return;
    float acc = ((a0 + a1) + (a2 + a3)) + ((a4 + a5) + (a6 + a7));
    size_t o = (size_t)n * F + f;
    if (EPI == 1) acc = 2.f * acc - aux[o];
    else if (EPI == 2) acc = aux[o] + 2.f * acc;
    y[o] = acc;
}

// ---------------- block-1 combine: cheb + bias + relu + tconv + relu ----------------
// One merged launch; blockIdx range selects branch (compile-time T per body).
template <int T, int OFF, int BROFF>
__device__ __forceinline__ void combine1_body(
        int unit, const float* __restrict__ xcat, const float* __restrict__ t1cat,
        const float* __restrict__ t2cat, float* __restrict__ z1cat,
        const float* __restrict__ W, const float* __restrict__ bg,
        const float* __restrict__ cw, const float* __restrict__ cb, int co) {
    int n = unit / NB, b = unit % NB;
    size_t rowbase = (size_t)n * F1T + OFF + b * T;
    float xv0 = 0.f, xv1 = 0.f, xv2 = 0.f;
    if (co < T) {
        xv0 = xcat[rowbase + co];
        xv1 = t1cat[rowbase + co];
        xv2 = t2cat[rowbase + co];
    }
    float acc = bg[co];
    #pragma unroll
    for (int i = 0; i < T; ++i)
        acc += __shfl(xv0, i) * W[i * 64 + co];
    #pragma unroll
    for (int i = 0; i < T; ++i)
        acc += __shfl(xv1, i) * W[(T + i) * 64 + co];
    #pragma unroll
    for (int i = 0; i < T; ++i)
        acc += __shfl(xv2, i) * W[(2 * T + i) * 64 + co];
    float z = fmaxf(acc, 0.f);
    float left  = __shfl_up(z, 1);
    float right = __shfl_down(z, 1);
    if (co == 0) left = 0.f;
    if (co == 63) right = 0.f;
    float w0 = cw[0], w1 = cw[1], w2 = cw[2], bb = cb[0];
    float o = fmaxf(w0 * left + w1 * z + w2 * right + bb, 0.f);
    z1cat[(size_t)n * Z1T + BROFF + b * 64 + co] = o;
}

__global__ void combine1_all_kernel(const float* __restrict__ xcat,
                                    const float* __restrict__ t1cat,
                                    const float* __restrict__ t2cat,
                                    float* __restrict__ z1cat, BrW P) {
    int wid = threadIdx.x >> 6;
    int co = threadIdx.x & 63;
    int b = blockIdx.x;
    if (b < 6000) {
        int unit = b * 4 + wid;
        combine1_body<24, 0, 0>(unit, xcat, t1cat, t2cat, z1cat,
                                P.W1[0], P.b1[0], P.c1w[0], P.c1b[0], co);
    } else if (b < 12000) {
        int unit = (b - 6000) * 4 + wid;
        combine1_body<12, 192, 512>(unit, xcat, t1cat, t2cat, z1cat,
                                    P.W1[1], P.b1[1], P.c1w[1], P.c1b[1], co);
    } else {
        int unit = (b - 12000) * 4 + wid;
        combine1_body<24, 288, 1024>(unit, xcat, t1cat, t2cat, z1cat,
                                     P.W1[2], P.b1[2], P.c1w[2], P.c1b[2], co);
    }
}

// ---------------- tiled y-GEMM: 96 rows x 96 cols per block, K=64 ----------------
#define GR 96
__global__ void __launch_bounds__(256, 2)
gemmy_kernel(const float* __restrict__ z1cat, float* __restrict__ y1cat,
             float* __restrict__ y2cat, float* __restrict__ c0cat, BrW P) {
    int tile = blockIdx.x;   // 0..249
    int br = blockIdx.y;
    __shared__ float sW[64 * 96];        // 24 KB; sW[k*96 + j*3 + m] = W[m][k][j]
    __shared__ float sZ[GR][65];         // 24.4 KB, padded
    const float* W = P.W2[br];           // (3, 64, 32)
    for (int i = threadIdx.x; i < 6144; i += 256) {
        int k = i / 96, c = i % 96;
        int j = c / 3, m = c % 3;
        sW[i] = W[m * 2048 + k * 32 + j];
    }
    int row0 = tile * GR;
    for (int i = threadIdx.x; i < GR * 64; i += 256) {
        int r = i >> 6, k = i & 63;
        int rg = row0 + r;
        int n = rg >> 3, b = rg & 7;
        sZ[r][k] = z1cat[(size_t)n * Z1T + br * 512 + b * 64 + k];
    }
    __syncthreads();

    int rq = threadIdx.x >> 3;       // 0..31 -> rows rq*3 .. rq*3+2
    int g = threadIdx.x & 7;         // cols g*12 .. g*12+11
    float acc[3][12];
    #pragma unroll
    for (int rr = 0; rr < 3; ++rr)
        #pragma unroll
        for (int j = 0; j < 12; ++j) acc[rr][j] = 0.f;

    #pragma unroll 4
    for (int k = 0; k < 64; ++k) {
        const float4* wr = reinterpret_cast<const float4*>(sW + k * 96 + g * 12);
        float4 wa = wr[0], wb = wr[1], wc = wr[2];
        #pragma unroll
        for (int rr = 0; rr < 3; ++rr) {
            float zv = sZ[rq * 3 + rr][k];
            acc[rr][0] += zv * wa.x; acc[rr][1] += zv * wa.y;
            acc[rr][2] += zv * wa.z; acc[rr][3] += zv * wa.w;
            acc[rr][4] += zv * wb.x; acc[rr][5] += zv * wb.y;
            acc[rr][6] += zv * wb.z; acc[rr][7] += zv * wb.w;
            acc[rr][8] += zv * wc.x; acc[rr][9] += zv * wc.y;
            acc[rr][10] += zv * wc.z; acc[rr][11] += zv * wc.w;
        }
    }

    const float* b2 = P.b2[br];
    float bj0 = b2[g * 4 + 0], bj1 = b2[g * 4 + 1], bj2 = b2[g * 4 + 2], bj3 = b2[g * 4 + 3];
    #pragma unroll
    for (int rr = 0; rr < 3; ++rr) {
        int rg = row0 + rq * 3 + rr;
        int n = rg >> 3, b = rg & 7;
        size_t obase = (size_t)n * F2T + br * 256 + b * 32;
        float bj[4] = {bj0, bj1, bj2, bj3};
        #pragma unroll
        for (int jj = 0; jj < 4; ++jj) {
            int j = g * 4 + jj;
            float a0 = acc[rr][jj * 3 + 0], a1 = acc[rr][jj * 3 + 1], a2 = acc[rr][jj * 3 + 2];
            y1cat[obase + j] = a1;
            y2cat[obase + j] = a2;
            c0cat[obase + j] = a0 - a2 + bj[jj];
        }
    }
}

// ---------------- block-2 combine + final linear + fusion, per node ----------------
__global__ void combine2_final_kernel(const float* __restrict__ c0cat,
                                      const float* __restrict__ vcat,
                                      const float* __restrict__ WD, const float* __restrict__ bD,
                                      float* __restrict__ out, BrW P) {
    int n = blockIdx.x;
    __shared__ float z2[3][NB][32];
    int unit = threadIdx.x >> 5;      // 0..23
    int co = threadIdx.x & 31;
    int br = unit >> 3, b = unit & 7;
    size_t o = (size_t)n * F2T + br * 256 + b * 32 + co;
    float a = fmaxf(c0cat[o] + vcat[o], 0.f);
    float left  = __shfl_up(a, 1);
    float right = __shfl_down(a, 1);
    if (co == 0) left = 0.f;
    if (co == 31) right = 0.f;
    float w0 = P.c2w[br][0], w1 = P.c2w[br][1], w2 = P.c2w[br][2], bb = P.c2b[br][0];
    z2[br][b][co] = fmaxf(w0 * left + w1 * a + w2 * right + bb, 0.f);
    __syncthreads();
    if (threadIdx.x < NB * TP) {
        int b2 = threadIdx.x / TP, tp = threadIdx.x % TP;
        float y = 0.f;
        for (int brr = 0; brr < 3; ++brr) {
            float s = bD[tp];
            const float* zz = z2[brr][b2];
            for (int c = 0; c < 32; ++c) s += zz[c] * WD[c * TP + tp];
            y += fmaxf(s, 0.f) * P.Fb[brr][tp];
        }
        out[((size_t)b2 * NN + n) * TP + tp] = y;
    }
}

// ---------------- launcher ----------------

static inline size_t align256(size_t x) { return (x + 255) & ~(size_t)255; }

extern "C" void kernel_launch(void* const* d_in, const int* in_sizes, int n_in,
                              void* d_out, int out_size, void* d_ws, size_t ws_size,
                              hipStream_t stream) {
    const float* Xh = (const float*)d_in[0];
    const float* Xd = (const float*)d_in[1];
    const float* Xw = (const float*)d_in[2];
    const float* A  = (const float*)d_in[3];
    const float* WD = (const float*)d_in[28];
    const float* bD = (const float*)d_in[29];

    BrW P;
    for (int br = 0; br < 3; ++br) {
        int base = 4 + br * 8;
        P.W1[br]  = (const float*)d_in[base + 0];
        P.b1[br]  = (const float*)d_in[base + 1];
        P.c1w[br] = (const float*)d_in[base + 2];
        P.c1b[br] = (const float*)d_in[base + 3];
        P.W2[br]  = (const float*)d_in[base + 4];
        P.b2[br]  = (const float*)d_in[base + 5];
        P.c2w[br] = (const float*)d_in[base + 6];
        P.c2b[br] = (const float*)d_in[base + 7];
        P.Fb[br]  = (const float*)d_in[30 + br];
    }

    char* p = (char*)d_ws;
    int*   colp  = (int*)p;   p += align256((size_t)NN * DMAX * 4);
    float* valp  = (float*)p; p += align256((size_t)NN * DMAX * 4);
    int*   cnt   = (int*)p;   p += align256(NN * 4);
    float* dinv  = (float*)p; p += align256(NN * 4);
    float* xcat  = (float*)p; p += align256((size_t)NN * F1T * 4);
    float* t1cat = (float*)p; p += align256((size_t)NN * F1T * 4);
    float* t2cat = (float*)p; p += align256((size_t)NN * F1T * 4);
    float* z1cat = (float*)p; p += align256((size_t)NN * Z1T * 4);
    float* y1cat = (float*)p; p += align256((size_t)NN * F2T * 4);
    float* y2cat = (float*)p; p += align256((size_t)NN * F2T * 4);
    float* c0cat = (float*)p; p += align256((size_t)NN * F2T * 4);
    float* scat  = (float*)p; p += align256((size_t)NN * F2T * 4);
    float* vcat  = (float*)p; p += align256((size_t)NN * F2T * 4);

    build_kernel<<<NN, 64, 0, stream>>>(A, colp, valp, cnt, dinv);
    scale_kernel<<<NN, DMAX, 0, stream>>>(colp, valp, cnt, dinv);
    pack_kernel<<<(NN * F1T + 255) / 256, 256, 0, stream>>>(Xh, Xd, Xw, xcat);

    // Block 1 (all branches packed, F=480): t1 = L x ; t2 = 2 L t1 - x
    spmm_kernel<F1T, 256, 0><<<6000, 256, 0, stream>>>(colp, valp, cnt, xcat, nullptr, t1cat);
    spmm_kernel<F1T, 256, 1><<<6000, 256, 0, stream>>>(colp, valp, cnt, t1cat, xcat, t2cat);
    combine1_all_kernel<<<18000, 256, 0, stream>>>(xcat, t1cat, t2cat, z1cat, P);

    // Block 2 W-first: y1,y2,c0 ; s = y1 + 2 L y2 ; v = L s ; out2 = relu(c0 + v)...
    gemmy_kernel<<<dim3(250, 3), 256, 0, stream>>>(z1cat, y1cat, y2cat, c0cat, P);
    spmm_kernel<F2T, 128, 2><<<18000, 128, 0, stream>>>(colp, valp, cnt, y2cat, y1cat, scat);
    spmm_kernel<F2T, 128, 0><<<18000, 128, 0, stream>>>(colp, valp, cnt, scat, nullptr, vcat);

    combine2_final_kernel<<<NN, 768, 0, stream>>>(c0cat, vcat, WD, bD, (float*)d_out, P);
}

// Round 11
// 174.677 us; speedup vs baseline: 1.4415x; 1.1542x over previous
//
#include <hip/hip_runtime.h>

#define NN 3000
#define NB 8
#define TP 12
#define DMAX 128
#define F1T 480    // block-1 packed features: h(8*24) + d(8*12) + w(8*24)
#define F2T 768    // block-2 packed features: 3 * 8 * 32
#define Z1T 1536   // z1 packed: 3 * 8 * 64

struct BrW {
    const float *W1[3]; const float *b1[3]; const float *c1w[3]; const float *c1b[3];
    const float *W2[3]; const float *b2[3]; const float *c2w[3]; const float *c2b[3];
    const float *Fb[3];
};

// ---------------- one-pass Laplacian build: degree + ballot-compact ----------------
__global__ void build_kernel(const float* __restrict__ A, int* __restrict__ colp,
                             float* __restrict__ valp, int* __restrict__ cnt,
                             float* __restrict__ dinv) {
    int n = blockIdx.x;
    int lane = threadIdx.x;
    const float* row = A + (size_t)n * NN;
    int base = 0;
    float s = 0.f;
    for (int start = 0; start < NN; start += 64) {
        int m = start + lane;
        float a = 0.f; bool nz = false;
        if (m < NN && m != n) {
            a = row[m];
            nz = (a != 0.f);
        }
        s += a;
        unsigned long long mask = __ballot(nz);
        int off = __popcll(mask & ((1ull << lane) - 1ull));
        if (nz) {
            int idx = base + off;
            if (idx < DMAX) { colp[n * DMAX + idx] = m; valp[n * DMAX + idx] = a; }
        }
        base += __popcll(mask);
    }
    for (int o = 32; o > 0; o >>= 1) s += __shfl_down(s, o);
    if (lane == 0) {
        cnt[n] = (base < DMAX) ? base : DMAX;
        dinv[n] = (s > 0.f) ? 1.0f / sqrtf(s) : 0.f;
    }
}

__global__ void scale_kernel(const int* __restrict__ colp, float* __restrict__ valp,
                             const int* __restrict__ cnt, const float* __restrict__ dinv) {
    int n = blockIdx.x;
    int j = threadIdx.x;
    if (j < cnt[n]) {
        int m = colp[n * DMAX + j];
        valp[n * DMAX + j] *= -dinv[n] * dinv[m];
    }
}

// ---------------- pack Xh|Xd|Xw (B,N,1,T) -> xcat (N, 480) ----------------
__global__ void pack_kernel(const float* __restrict__ Xh, const float* __restrict__ Xd,
                            const float* __restrict__ Xw, float* __restrict__ xcat) {
    int idx = blockIdx.x * blockDim.x + threadIdx.x;
    if (idx >= NN * F1T) return;
    int n = idx / F1T, r = idx % F1T;
    const float* src; int b, t, T;
    if (r < 192)      { src = Xh; T = 24; int rr = r;       b = rr / 24; t = rr % 24; }
    else if (r < 288) { src = Xd; T = 12; int rr = r - 192; b = rr / 12; t = rr % 12; }
    else              { src = Xw; T = 24; int rr = r - 288; b = rr / 24; t = rr % 24; }
    xcat[idx] = src[((size_t)b * NN + n) * T + t];
}

// ---------------- SpMM, scalar gathers, 16-deep ILP, XCD-swizzled slices ----------------
// EPI 0: y = Lx ; EPI 1: y = 2*Lx - aux ; EPI 2: y = aux + 2*Lx
template <int F, int SLICE, int EPI>
__global__ void spmm_kernel(const int* __restrict__ colp, const float* __restrict__ valp,
                            const int* __restrict__ cnt, const float* __restrict__ x,
                            const float* __restrict__ aux, float* __restrict__ y) {
    int nwg = gridDim.x;
    int q = nwg >> 3;
    int bid = blockIdx.x;
    int w = (bid & 7) * q + (bid >> 3);   // XCD-contiguous chunks (nwg % 8 == 0)
    int slice = w / NN;
    int n = w - slice * NN;
    int f = slice * SLICE + threadIdx.x;

    __shared__ int   scol[DMAX];
    __shared__ float sval[DMAX];
    int c = cnt[n];
    if (threadIdx.x < DMAX) {
        int j = threadIdx.x;
        bool ok = j < c;
        scol[j] = ok ? colp[n * DMAX + j] * F : 0;
        sval[j] = ok ? valp[n * DMAX + j] : 0.f;
    }
    __syncthreads();
    int c16 = (c + 15) & ~15;
    float a0 = 0.f, a1 = 0.f, a2 = 0.f, a3 = 0.f;
    float a4 = 0.f, a5 = 0.f, a6 = 0.f, a7 = 0.f;
    if (f < F) {
        for (int i = 0; i < c16; i += 16) {
            float g[16], w16[16];
            #pragma unroll
            for (int u = 0; u < 16; ++u) {
                int cc = scol[i + u];
                w16[u] = sval[i + u];
                g[u] = x[cc + f];
            }
            a0 += w16[0] * g[0];   a1 += w16[1] * g[1];
            a2 += w16[2] * g[2];   a3 += w16[3] * g[3];
            a4 += w16[4] * g[4];   a5 += w16[5] * g[5];
            a6 += w16[6] * g[6];   a7 += w16[7] * g[7];
            a0 += w16[8] * g[8];   a1 += w16[9] * g[9];
            a2 += w16[10] * g[10]; a3 += w16[11] * g[11];
            a4 += w16[12] * g[12]; a5 += w16[13] * g[13];
            a6 += w16[14] * g[14]; a7 += w16[15] * g[15];
        }
    }
    if (f >= F) return;
    float acc = ((a0 + a1) + (a2 + a3)) + ((a4 + a5) + (a6 + a7));
    size_t o = (size_t)n * F + f;
    if (EPI == 1) acc = 2.f * acc - aux[o];
    else if (EPI == 2) acc = aux[o] + 2.f * acc;
    y[o] = acc;
}

// ---------------- block-1 combine as tiled GEMM + tconv epilogue ----------------
// M=24000 units, K=3T (x||t1||t2; W(3,T,64) == (K,64) row-major), N=64.
// Block: 96 rows; thread (rq,g): 3 rows x 8 cols. tconv via 2 shfl/row.
template <int T, int OFF, int BROFF>
__device__ __forceinline__ void combine1_gemm_body(
        int tile, const float* __restrict__ xcat, const float* __restrict__ t1cat,
        const float* __restrict__ t2cat, float* __restrict__ z1cat,
        const float* __restrict__ W, const float* __restrict__ bg,
        const float* __restrict__ cw, const float* __restrict__ cb,
        float* sW, float* sX) {
    constexpr int K = 3 * T;
    constexpr int LDA = K + 1;
    int tid = threadIdx.x;
    // stage W (K,64) directly
    for (int i = tid; i < K * 64; i += 256) sW[i] = W[i];
    // stage 96 unit-rows: 12 n x 8 b, three sources
    int n0 = tile * 12;
    #pragma unroll
    for (int s = 0; s < 3; ++s) {
        const float* src = (s == 0) ? xcat : (s == 1) ? t1cat : t2cat;
        for (int i = tid; i < 96 * T; i += 256) {
            int n_l = i / (8 * T), rem = i % (8 * T);
            int b = rem / T, ii = rem % T;
            float v = src[(size_t)(n0 + n_l) * F1T + OFF + b * T + ii];
            sX[(n_l * 8 + b) * LDA + s * T + ii] = v;
        }
    }
    __syncthreads();

    int rq = tid >> 3;       // 0..31 -> rows rq*3..rq*3+2
    int g  = tid & 7;        // cols g*8..g*8+7
    float acc[3][8];
    #pragma unroll
    for (int r = 0; r < 3; ++r)
        #pragma unroll
        for (int j = 0; j < 8; ++j) acc[r][j] = 0.f;

    #pragma unroll 4
    for (int k = 0; k < K; ++k) {
        const float4* wr = reinterpret_cast<const float4*>(sW + k * 64 + g * 8);
        float4 wa = wr[0], wb = wr[1];
        #pragma unroll
        for (int r = 0; r < 3; ++r) {
            float zv = sX[(rq * 3 + r) * LDA + k];
            acc[r][0] += zv * wa.x; acc[r][1] += zv * wa.y;
            acc[r][2] += zv * wa.z; acc[r][3] += zv * wa.w;
            acc[r][4] += zv * wb.x; acc[r][5] += zv * wb.y;
            acc[r][6] += zv * wb.z; acc[r][7] += zv * wb.w;
        }
    }

    float bgv[8];
    #pragma unroll
    for (int j = 0; j < 8; ++j) bgv[j] = bg[g * 8 + j];
    float w0 = cw[0], w1 = cw[1], w2 = cw[2], bb = cb[0];

    #pragma unroll
    for (int r = 0; r < 3; ++r) {
        float z[8];
        #pragma unroll
        for (int j = 0; j < 8; ++j) z[j] = fmaxf(acc[r][j] + bgv[j], 0.f);
        float zl = __shfl_up(z[7], 1);    // left neighbor's col7 (valid when g>0)
        float zr = __shfl_down(z[0], 1);  // right neighbor's col0 (valid when g<7)
        float o[8];
        #pragma unroll
        for (int j = 0; j < 8; ++j) {
            float left  = (j > 0) ? z[j - 1] : ((g > 0) ? zl : 0.f);
            float right = (j < 7) ? z[j + 1] : ((g < 7) ? zr : 0.f);
            o[j] = fmaxf(w0 * left + w1 * z[j] + w2 * right + bb, 0.f);
        }
        int unit = tile * 96 + rq * 3 + r;
        int n = unit >> 3, b = unit & 7;
        float* dst = z1cat + (size_t)n * Z1T + BROFF + b * 64 + g * 8;
        reinterpret_cast<float4*>(dst)[0] = make_float4(o[0], o[1], o[2], o[3]);
        reinterpret_cast<float4*>(dst)[1] = make_float4(o[4], o[5], o[6], o[7]);
    }
}

__global__ void __launch_bounds__(256)
combine1_all_kernel(const float* __restrict__ xcat, const float* __restrict__ t1cat,
                    const float* __restrict__ t2cat, float* __restrict__ z1cat, BrW P) {
    __shared__ float sW[72 * 64];    // 18 KB (max K=72)
    __shared__ float sX[96 * 73];    // 28 KB (max LDA=73)
    int b = blockIdx.x;
    if (b < 250) {
        combine1_gemm_body<24, 0, 0>(b, xcat, t1cat, t2cat, z1cat,
                                     P.W1[0], P.b1[0], P.c1w[0], P.c1b[0], sW, sX);
    } else if (b < 500) {
        combine1_gemm_body<12, 192, 512>(b - 250, xcat, t1cat, t2cat, z1cat,
                                         P.W1[1], P.b1[1], P.c1w[1], P.c1b[1], sW, sX);
    } else {
        combine1_gemm_body<24, 288, 1024>(b - 500, xcat, t1cat, t2cat, z1cat,
                                          P.W1[2], P.b1[2], P.c1w[2], P.c1b[2], sW, sX);
    }
}

// ---------------- tiled y-GEMM: 96 rows x 96 cols per block, K=64 ----------------
#define GR 96
__global__ void __launch_bounds__(256, 2)
gemmy_kernel(const float* __restrict__ z1cat, float* __restrict__ y1cat,
             float* __restrict__ y2cat, float* __restrict__ c0cat, BrW P) {
    int tile = blockIdx.x;   // 0..249
    int br = blockIdx.y;
    __shared__ float sW[64 * 96];        // 24 KB; sW[k*96 + j*3 + m] = W[m][k][j]
    __shared__ float sZ[GR][65];         // 24.4 KB, padded
    const float* W = P.W2[br];           // (3, 64, 32)
    for (int i = threadIdx.x; i < 6144; i += 256) {
        int k = i / 96, c = i % 96;
        int j = c / 3, m = c % 3;
        sW[i] = W[m * 2048 + k * 32 + j];
    }
    int row0 = tile * GR;
    for (int i = threadIdx.x; i < GR * 64; i += 256) {
        int r = i >> 6, k = i & 63;
        int rg = row0 + r;
        int n = rg >> 3, b = rg & 7;
        sZ[r][k] = z1cat[(size_t)n * Z1T + br * 512 + b * 64 + k];
    }
    __syncthreads();

    int rq = threadIdx.x >> 3;       // 0..31 -> rows rq*3 .. rq*3+2
    int g = threadIdx.x & 7;         // cols g*12 .. g*12+11
    float acc[3][12];
    #pragma unroll
    for (int rr = 0; rr < 3; ++rr)
        #pragma unroll
        for (int j = 0; j < 12; ++j) acc[rr][j] = 0.f;

    #pragma unroll 4
    for (int k = 0; k < 64; ++k) {
        const float4* wr = reinterpret_cast<const float4*>(sW + k * 96 + g * 12);
        float4 wa = wr[0], wb = wr[1], wc = wr[2];
        #pragma unroll
        for (int rr = 0; rr < 3; ++rr) {
            float zv = sZ[rq * 3 + rr][k];
            acc[rr][0] += zv * wa.x; acc[rr][1] += zv * wa.y;
            acc[rr][2] += zv * wa.z; acc[rr][3] += zv * wa.w;
            acc[rr][4] += zv * wb.x; acc[rr][5] += zv * wb.y;
            acc[rr][6] += zv * wb.z; acc[rr][7] += zv * wb.w;
            acc[rr][8] += zv * wc.x; acc[rr][9] += zv * wc.y;
            acc[rr][10] += zv * wc.z; acc[rr][11] += zv * wc.w;
        }
    }

    const float* b2 = P.b2[br];
    float bj0 = b2[g * 4 + 0], bj1 = b2[g * 4 + 1], bj2 = b2[g * 4 + 2], bj3 = b2[g * 4 + 3];
    #pragma unroll
    for (int rr = 0; rr < 3; ++rr) {
        int rg = row0 + rq * 3 + rr;
        int n = rg >> 3, b = rg & 7;
        size_t obase = (size_t)n * F2T + br * 256 + b * 32;
        float bj[4] = {bj0, bj1, bj2, bj3};
        #pragma unroll
        for (int jj = 0; jj < 4; ++jj) {
            int j = g * 4 + jj;
            float a0 = acc[rr][jj * 3 + 0], a1 = acc[rr][jj * 3 + 1], a2 = acc[rr][jj * 3 + 2];
            y1cat[obase + j] = a1;
            y2cat[obase + j] = a2;
            c0cat[obase + j] = a0 - a2 + bj[jj];
        }
    }
}

// ---------------- block-2 combine + final linear + fusion, per node ----------------
__global__ void combine2_final_kernel(const float* __restrict__ c0cat,
                                      const float* __restrict__ vcat,
                                      const float* __restrict__ WD, const float* __restrict__ bD,
                                      float* __restrict__ out, BrW P) {
    int n = blockIdx.x;
    __shared__ float z2[3][NB][32];
    int unit = threadIdx.x >> 5;      // 0..23
    int co = threadIdx.x & 31;
    int br = unit >> 3, b = unit & 7;
    size_t o = (size_t)n * F2T + br * 256 + b * 32 + co;
    float a = fmaxf(c0cat[o] + vcat[o], 0.f);
    float left  = __shfl_up(a, 1);
    float right = __shfl_down(a, 1);
    if (co == 0) left = 0.f;
    if (co == 31) right = 0.f;
    float w0 = P.c2w[br][0], w1 = P.c2w[br][1], w2 = P.c2w[br][2], bb = P.c2b[br][0];
    z2[br][b][co] = fmaxf(w0 * left + w1 * a + w2 * right + bb, 0.f);
    __syncthreads();
    if (threadIdx.x < NB * TP) {
        int b2 = threadIdx.x / TP, tp = threadIdx.x % TP;
        float y = 0.f;
        for (int brr = 0; brr < 3; ++brr) {
            float s = bD[tp];
            const float* zz = z2[brr][b2];
            for (int c = 0; c < 32; ++c) s += zz[c] * WD[c * TP + tp];
            y += fmaxf(s, 0.f) * P.Fb[brr][tp];
        }
        out[((size_t)b2 * NN + n) * TP + tp] = y;
    }
}

// ---------------- launcher ----------------

static inline size_t align256(size_t x) { return (x + 255) & ~(size_t)255; }

extern "C" void kernel_launch(void* const* d_in, const int* in_sizes, int n_in,
                              void* d_out, int out_size, void* d_ws, size_t ws_size,
                              hipStream_t stream) {
    const float* Xh = (const float*)d_in[0];
    const float* Xd = (const float*)d_in[1];
    const float* Xw = (const float*)d_in[2];
    const float* A  = (const float*)d_in[3];
    const float* WD = (const float*)d_in[28];
    const float* bD = (const float*)d_in[29];

    BrW P;
    for (int br = 0; br < 3; ++br) {
        int base = 4 + br * 8;
        P.W1[br]  = (const float*)d_in[base + 0];
        P.b1[br]  = (const float*)d_in[base + 1];
        P.c1w[br] = (const float*)d_in[base + 2];
        P.c1b[br] = (const float*)d_in[base + 3];
        P.W2[br]  = (const float*)d_in[base + 4];
        P.b2[br]  = (const float*)d_in[base + 5];
        P.c2w[br] = (const float*)d_in[base + 6];
        P.c2b[br] = (const float*)d_in[base + 7];
        P.Fb[br]  = (const float*)d_in[30 + br];
    }

    char* p = (char*)d_ws;
    int*   colp  = (int*)p;   p += align256((size_t)NN * DMAX * 4);
    float* valp  = (float*)p; p += align256((size_t)NN * DMAX * 4);
    int*   cnt   = (int*)p;   p += align256(NN * 4);
    float* dinv  = (float*)p; p += align256(NN * 4);
    float* xcat  = (float*)p; p += align256((size_t)NN * F1T * 4);
    float* t1cat = (float*)p; p += align256((size_t)NN * F1T * 4);
    float* t2cat = (float*)p; p += align256((size_t)NN * F1T * 4);
    float* z1cat = (float*)p; p += align256((size_t)NN * Z1T * 4);
    float* y1cat = (float*)p; p += align256((size_t)NN * F2T * 4);
    float* y2cat = (float*)p; p += align256((size_t)NN * F2T * 4);
    float* c0cat = (float*)p; p += align256((size_t)NN * F2T * 4);
    float* scat  = (float*)p; p += align256((size_t)NN * F2T * 4);
    float* vcat  = (float*)p; p += align256((size_t)NN * F2T * 4);

    build_kernel<<<NN, 64, 0, stream>>>(A, colp, valp, cnt, dinv);
    scale_kernel<<<NN, DMAX, 0, stream>>>(colp, valp, cnt, dinv);
    pack_kernel<<<(NN * F1T + 255) / 256, 256, 0, stream>>>(Xh, Xd, Xw, xcat);

    // Block 1 (all branches packed, F=480): t1 = L x ; t2 = 2 L t1 - x
    spmm_kernel<F1T, 256, 0><<<6000, 256, 0, stream>>>(colp, valp, cnt, xcat, nullptr, t1cat);
    spmm_kernel<F1T, 256, 1><<<6000, 256, 0, stream>>>(colp, valp, cnt, t1cat, xcat, t2cat);
    combine1_all_kernel<<<750, 256, 0, stream>>>(xcat, t1cat, t2cat, z1cat, P);

    // Block 2 W-first: y1,y2,c0 ; s = y1 + 2 L y2 ; v = L s ; out2 = relu(c0 + v)...
    gemmy_kernel<<<dim3(250, 3), 256, 0, stream>>>(z1cat, y1cat, y2cat, c0cat, P);
    spmm_kernel<F2T, 128, 2><<<18000, 128, 0, stream>>>(colp, valp, cnt, y2cat, y1cat, scat);
    spmm_kernel<F2T, 128, 0><<<18000, 128, 0, stream>>>(colp, valp, cnt, scat, nullptr, vcat);

    combine2_final_kernel<<<NN, 768, 0, stream>>>(c0cat, vcat, WD, bD, (float*)d_out, P);
}